// Round 8
// baseline (142.261 us; speedup 1.0000x reference)
//
#include <hip/hip_runtime.h>
#include <hip/hip_bf16.h>

#define NB   32
#define DIMK 512
#define MM   32
#define ZZ   64
#define MZV  2048
#define VOC  50257

typedef __attribute__((ext_vector_type(8))) short  short8;   // 8 bf16 = 4 VGPR
typedef __attribute__((ext_vector_type(4))) float  f32x4;
typedef __attribute__((ext_vector_type(8))) unsigned short ushort8;

// ws layout in floats
#define WS_W      0                       // [NB][MZV] raw scores (incl. log mask)
#define WS_PVEC   (WS_W + NB*MZV)         // [NB][MM][DIMK] partial weighted vecs
#define WS_LSTAT  (WS_PVEC + NB*MM*DIMK)  // [NB][MM][2] (max, sum)
#define WS_GSTATW (WS_LSTAT + NB*MM*2)    // [NB][2] global (max,sum) copy branch
#define WS_MIX    (WS_GSTATW + NB*2)      // [NB][2]
#define WS_GPART  (WS_MIX + NB*2)         // [NB][32][2] gen softmax partials
#define WS_H      (WS_GPART + NB*32*2)    // [NB][1024] bf16 h (as ushort)

// pack 8 f32 -> 8 bf16 (RNE) via v_cvt_pk_bf16_f32 (compiler-generated)
__device__ __forceinline__ ushort8 cvt8(float4 a, float4 b) {
    union { ushort8 u; __hip_bfloat162 h[4]; } r;
    r.h[0] = __float22bfloat162_rn(make_float2(a.x, a.y));
    r.h[1] = __float22bfloat162_rn(make_float2(a.z, a.w));
    r.h[2] = __float22bfloat162_rn(make_float2(b.x, b.y));
    r.h[3] = __float22bfloat162_rn(make_float2(b.z, b.w));
    return r.u;
}

// K0: h = concat(encsumm, enc) converted to bf16, contiguous per batch
__global__ void k0_stageh(const float* __restrict__ encsumm, const float* __restrict__ enc,
                          float* __restrict__ ws)
{
    int b = blockIdx.x;
    int c = threadIdx.x * 4;                       // 0..1020
    const float* src = (c < DIMK) ? (encsumm + b*DIMK + c) : (enc + b*DIMK + (c - DIMK));
    float4 v = *(const float4*)src;
    union { ushort4 u; __hip_bfloat162 h[2]; } o;
    o.h[0] = __float22bfloat162_rn(make_float2(v.x, v.y));
    o.h[1] = __float22bfloat162_rn(make_float2(v.z, v.w));
    *(ushort4*)((unsigned short*)(ws + WS_H) + b*1024 + c) = o.u;
}

// K1: per (b,m) block — scores + online-softmax weighted sum, memencs read ONCE
__global__ __launch_bounds__(256) void k1_mem(
    const float* __restrict__ enc, const float* __restrict__ embsumm,
    const float* __restrict__ memencs, const float* __restrict__ memembsumm,
    const float* __restrict__ memmask, float* __restrict__ ws)
{
    int blk = blockIdx.x;
    int b = blk >> 5, m = blk & 31;
    int tid = threadIdx.x, wid = tid >> 6, lane = tid & 63;
    int c0 = lane * 4, c1 = c0 + 256;
    const float* encb = enc + b * DIMK;
    const float* embb = embsumm + b * DIMK;
    float4 qe0 = *(const float4*)(encb + c0);
    float4 qe1 = *(const float4*)(encb + c1);
    float4 qm0 = *(const float4*)(embb + c0);
    float4 qm1 = *(const float4*)(embb + c1);
    const float* meb = memencs    + (long)(b*MM + m) * ZZ * DIMK;
    const float* mmb = memembsumm + (long)(b*MM + m) * ZZ * DIMK;
    const float* mkb = memmask    + (long)(b*MM + m) * ZZ;
    float* w_ws = ws + WS_W + b*MZV + m*ZZ;

    float lmax = -3.0e38f, lsum = 0.f;
    float4 a0 = make_float4(0.f,0.f,0.f,0.f), a1 = make_float4(0.f,0.f,0.f,0.f);

    for (int z = wid; z < ZZ; z += 4) {
        const float* mer = meb + z*DIMK;
        const float* mmr = mmb + z*DIMK;
        float4 e0 = *(const float4*)(mer + c0);
        float4 e1 = *(const float4*)(mer + c1);
        float4 s0 = *(const float4*)(mmr + c0);
        float4 s1 = *(const float4*)(mmr + c1);
        float d = e0.x*qe0.x + e0.y*qe0.y + e0.z*qe0.z + e0.w*qe0.w
                + e1.x*qe1.x + e1.y*qe1.y + e1.z*qe1.z + e1.w*qe1.w
                + s0.x*qm0.x + s0.y*qm0.y + s0.z*qm0.z + s0.w*qm0.w
                + s1.x*qm1.x + s1.y*qm1.y + s1.z*qm1.z + s1.w*qm1.w;
        #pragma unroll
        for (int off = 32; off; off >>= 1) d += __shfl_xor(d, off);
        d += logf(mkb[z]);                 // mask=1 -> +0; mask=0 -> -inf
        if (lane == 0) w_ws[z] = d;
        float nm = fmaxf(lmax, d);
        float sc = __expf(lmax - nm);
        float e  = __expf(d - nm);
        lsum = lsum * sc + e;
        a0.x = a0.x*sc + e*e0.x; a0.y = a0.y*sc + e*e0.y;
        a0.z = a0.z*sc + e*e0.z; a0.w = a0.w*sc + e*e0.w;
        a1.x = a1.x*sc + e*e1.x; a1.y = a1.y*sc + e*e1.y;
        a1.z = a1.z*sc + e*e1.z; a1.w = a1.w*sc + e*e1.w;
        lmax = nm;
    }

    __shared__ float sacc[4][DIMK];
    __shared__ float sst[4][2];
    *(float4*)&sacc[wid][c0] = a0;
    *(float4*)&sacc[wid][c1] = a1;
    if (lane == 0) { sst[wid][0] = lmax; sst[wid][1] = lsum; }
    __syncthreads();
    float bm = fmaxf(fmaxf(sst[0][0], sst[1][0]), fmaxf(sst[2][0], sst[3][0]));
    float sc0 = __expf(sst[0][0]-bm), sc1 = __expf(sst[1][0]-bm);
    float sc2 = __expf(sst[2][0]-bm), sc3 = __expf(sst[3][0]-bm);
    float bs = sst[0][1]*sc0 + sst[1][1]*sc1 + sst[2][1]*sc2 + sst[3][1]*sc3;
    int d0 = tid * 2;
    float2 v0 = *(float2*)&sacc[0][d0];
    float2 v1 = *(float2*)&sacc[1][d0];
    float2 v2 = *(float2*)&sacc[2][d0];
    float2 v3 = *(float2*)&sacc[3][d0];
    float p0 = v0.x*sc0 + v1.x*sc1 + v2.x*sc2 + v3.x*sc3;
    float p1 = v0.y*sc0 + v1.y*sc1 + v2.y*sc2 + v3.y*sc3;
    float* pv = ws + WS_PVEC + (long)(b*MM+m)*DIMK + d0;
    pv[0] = p0; pv[1] = p1;
    if (tid == 0) { float* ls = ws + WS_LSTAT + (b*MM+m)*2; ls[0] = bm; ls[1] = bs; }
}

// K2: combine the 32 m-partials per b -> mem_enc_summ (output 1) + global (max,sum)
// + (merged k3) mixer gates computed by wave 0
__global__ __launch_bounds__(256) void k2_comb(
    const float* __restrict__ encsumm, const float* __restrict__ enc,
    const float* __restrict__ W_mix, const float* __restrict__ b_mix,
    float* __restrict__ out, float* __restrict__ ws)
{
    int b = blockIdx.x, tid = threadIdx.x;
    const float* ls = ws + WS_LSTAT + b*MM*2;
    float gm = -3.0e38f;
    #pragma unroll
    for (int m = 0; m < MM; m++) gm = fmaxf(gm, ls[m*2]);
    float gs = 0.f;
    #pragma unroll
    for (int m = 0; m < MM; m++) gs += ls[m*2+1] * __expf(ls[m*2] - gm);
    if (tid == 0) { ws[WS_GSTATW + b*2] = gm; ws[WS_GSTATW + b*2 + 1] = gs; }
    float inv = 1.0f / gs;
    int d0 = tid * 2;
    float p0 = 0.f, p1 = 0.f;
    for (int m = 0; m < MM; m++) {
        float sc = __expf(ls[m*2] - gm);
        const float* pv = ws + WS_PVEC + (long)(b*MM+m)*DIMK + d0;
        p0 += pv[0]*sc; p1 += pv[1]*sc;
    }
    out[(long)NB*VOC + b*DIMK + d0]     = p0 * inv;
    out[(long)NB*VOC + b*DIMK + d0 + 1] = p1 * inv;

    // ---- merged mixer (wave 0 only) ----
    if (tid < 64) {
        int l = tid;
        float m0 = 0.f, m1 = 0.f;
        #pragma unroll
        for (int p = 0; p < 4; p++) {
            int cc = l*4 + p*256;
            float4 h4 = (cc < 512) ? *(const float4*)(encsumm + b*DIMK + cc)
                                   : *(const float4*)(enc + b*DIMK + cc - 512);
            float4 w0 = *(const float4*)(W_mix + cc);
            float4 w1 = *(const float4*)(W_mix + 1024 + cc);
            m0 += h4.x*w0.x + h4.y*w0.y + h4.z*w0.z + h4.w*w0.w;
            m1 += h4.x*w1.x + h4.y*w1.y + h4.z*w1.z + h4.w*w1.w;
        }
        #pragma unroll
        for (int off = 32; off; off >>= 1) { m0 += __shfl_xor(m0, off); m1 += __shfl_xor(m1, off); }
        if (l == 0) {
            m0 += b_mix[0]; m1 += b_mix[1];
            float mx = fmaxf(m0, m1);
            float e0 = __expf(m0-mx), e1 = __expf(m1-mx);
            float s = e0 + e1;
            ws[WS_MIX + b*2] = e0/s; ws[WS_MIX + b*2 + 1] = e1/s;
        }
    }
}

// K4 v8 (MFMA + depth-2 prefetch + forced occupancy): block = 64 v x 32 b,
// 4 waves, __launch_bounds__(256,4) -> VGPR<=128 -> >=4 blocks/CU.
// Chunk = 64 k; two named staging sets (A=even chunks, B=odd), loads issued
// ~2 iterations before use; double-buffered LDS; one barrier per chunk.
__global__ __launch_bounds__(256, 4) void k4_gemm(
    const unsigned short* __restrict__ hbf,
    const float* __restrict__ W_out, const float* __restrict__ b_out,
    const float* __restrict__ unk, float* __restrict__ logits)
{
    __shared__ __align__(16) unsigned short b_lds[2][8*64*8];   // 2 x 8 KB
    __shared__ __align__(16) unsigned short a_lds[2][8*32*8];   // 2 x 4 KB
    int tid = threadIdx.x, wid = tid >> 6, lane = tid & 63;
    int vt = blockIdx.x * 64;

    // W staging: thread owns 16 contiguous floats (64B) of one W row per chunk
    int r = tid >> 2, q = tid & 3;
    long grow = min(vt + r, VOC - 1);
    const float* wbase = W_out + grow * 1024 + q * 16;
    // A staging: thread owns 1 granule (8 bf16) per chunk
    int ar = tid >> 3, ag = tid & 7;
    const unsigned short* abase = hbf + ar * 1024 + ag * 8;

    int lg = lane >> 4, ln = lane & 15;
    int vrow = wid*16 + ln;

    f32x4 acc0 = {0.f,0.f,0.f,0.f};
    f32x4 acc1 = {0.f,0.f,0.f,0.f};
    float4 Af0, Af1, Af2, Af3; ushort8 Aa;    // staging set A (even chunks)
    float4 Bf0, Bf1, Bf2, Bf3; ushort8 Ba;    // staging set B (odd chunks)

    int g0 = 2*q, g1 = 2*q + 1;
    int bw0 = (g0*64 + (r ^ ((g0 & 3) << 2))) * 8;
    int bw1 = (g1*64 + (r ^ ((g1 & 3) << 2))) * 8;
    int aw  = (ag*32 + (ar ^ ag)) * 8;

#define LOAD_A(c) do { const float* wp = wbase + (c)*64;                 \
        Af0 = *(const float4*)(wp);      Af1 = *(const float4*)(wp+4);   \
        Af2 = *(const float4*)(wp+8);    Af3 = *(const float4*)(wp+12);  \
        Aa  = *(const ushort8*)(abase + (c)*64); } while (0)
#define LOAD_B(c) do { const float* wp = wbase + (c)*64;                 \
        Bf0 = *(const float4*)(wp);      Bf1 = *(const float4*)(wp+4);   \
        Bf2 = *(const float4*)(wp+8);    Bf3 = *(const float4*)(wp+12);  \
        Ba  = *(const ushort8*)(abase + (c)*64); } while (0)
#define WRITE_A(buf) do {                                \
        *(ushort8*)&b_lds[buf][bw0] = cvt8(Af0, Af1);    \
        *(ushort8*)&b_lds[buf][bw1] = cvt8(Af2, Af3);    \
        *(ushort8*)&a_lds[buf][aw]  = Aa; } while (0)
#define WRITE_B(buf) do {                                \
        *(ushort8*)&b_lds[buf][bw0] = cvt8(Bf0, Bf1);    \
        *(ushort8*)&b_lds[buf][bw1] = cvt8(Bf2, Bf3);    \
        *(ushort8*)&a_lds[buf][aw]  = Ba; } while (0)
#define COMPUTE(buf) do {                                                          \
        _Pragma("unroll")                                                          \
        for (int s = 0; s < 2; ++s) {                                              \
            int g = s*4 + lg;                                                      \
            short8 bfrag = *(const short8*)&b_lds[buf][(g*64 + (vrow ^ ((g&3)<<2)))*8]; \
            short8 a0 = *(const short8*)&a_lds[buf][(g*32 + (ln ^ g))*8];          \
            short8 a1 = *(const short8*)&a_lds[buf][(g*32 + ((ln + 16) ^ g))*8];   \
            acc0 = __builtin_amdgcn_mfma_f32_16x16x32_bf16(a0, bfrag, acc0, 0, 0, 0); \
            acc1 = __builtin_amdgcn_mfma_f32_16x16x32_bf16(a1, bfrag, acc1, 0, 0, 0); \
        } } while (0)

    // prologue: A<-chunk0, B<-chunk1, write chunk0, A<-chunk2
    LOAD_A(0); LOAD_B(1);
    WRITE_A(0);
    LOAD_A(2);
    __syncthreads();

    for (int cc = 0; cc < 8; ++cc) {
        int c0 = cc*2, c1 = c0 + 1;
        // ---- even iter: compute buf0 (chunk c0) ----
        if (cc >= 1 && c0 + 2 < 16) LOAD_A(c0 + 2);   // A <- even chunk, ~2 iters ahead
        COMPUTE(0);
        WRITE_B(1);                                   // chunk c1 -> buf1
        __syncthreads();
        // ---- odd iter: compute buf1 (chunk c1) ----
        if (c1 + 2 < 16) LOAD_B(c1 + 2);              // B <- odd chunk, ~2 iters ahead
        COMPUTE(1);
        if (c1 < 15) WRITE_A(0);                      // chunk c1+1 -> buf0
        __syncthreads();
    }
#undef LOAD_A
#undef LOAD_B
#undef WRITE_A
#undef WRITE_B
#undef COMPUTE

    // epilogue: C/D layout col=lane&15, row=(lane>>4)*4+reg  (m89-verified)
    int v = vt + vrow;
    if (v < VOC) {
        float bias = b_out[v] + logf(unk[v]);
        #pragma unroll
        for (int rr = 0; rr < 4; ++rr) {
            int m = lg*4 + rr;
            logits[(long)m*VOC + v]        = acc0[rr] + bias;
            logits[(long)(m+16)*VOC + v]   = acc1[rr] + bias;
        }
    }
}

// K5: gen softmax stats, 32 chunks per b
__global__ __launch_bounds__(256) void k5_gstat(const float* __restrict__ logits, float* __restrict__ ws)
{
    int chunk = blockIdx.x, b = blockIdx.y, tid = threadIdx.x;
    const int CH = (VOC + 31) / 32;
    int v0 = chunk * CH;
    int v1 = min(VOC, v0 + CH);
    float m = -3.0e38f, s = 0.f;
    for (int v = v0 + tid; v < v1; v += 256) {
        float x = logits[(long)b*VOC + v];
        float nm = fmaxf(m, x);
        s = s*__expf(m - nm) + __expf(x - nm);
        m = nm;
    }
    #pragma unroll
    for (int off = 32; off; off >>= 1) {
        float om = __shfl_xor(m, off), os = __shfl_xor(s, off);
        float nm = fmaxf(m, om);
        s = s*__expf(m - nm) + os*__expf(om - nm);
        m = nm;
    }
    __shared__ float sm[4], ssum[4];
    int wid = tid >> 6, lane = tid & 63;
    if (lane == 0) { sm[wid] = m; ssum[wid] = s; }
    __syncthreads();
    if (tid == 0) {
        float gm = fmaxf(fmaxf(sm[0], sm[1]), fmaxf(sm[2], sm[3]));
        float gs = ssum[0]*__expf(sm[0]-gm) + ssum[1]*__expf(sm[1]-gm)
                 + ssum[2]*__expf(sm[2]-gm) + ssum[3]*__expf(sm[3]-gm);
        ws[WS_GPART + (b*32 + chunk)*2]     = gm;
        ws[WS_GPART + (b*32 + chunk)*2 + 1] = gs;
    }
}

// K6: probs = mix0 * softmax(logits), in place; merges the 32 chunk partials inline
__global__ __launch_bounds__(256) void k6_final(float* __restrict__ probs, const float* __restrict__ ws)
{
    int v = blockIdx.x*256 + threadIdx.x;
    int b = blockIdx.y;
    float gm = -3.0e38f;
    #pragma unroll
    for (int i = 0; i < 32; ++i) gm = fmaxf(gm, ws[WS_GPART + (b*32+i)*2]);
    float gs = 0.f;
    #pragma unroll
    for (int i = 0; i < 32; ++i)
        gs += ws[WS_GPART + (b*32+i)*2 + 1] * __expf(ws[WS_GPART + (b*32+i)*2] - gm);
    if (v >= VOC) return;
    float mix0 = ws[WS_MIX + b*2];
    long idx = (long)b*VOC + v;
    probs[idx] = mix0 * __expf(probs[idx] - gm) / gs;
}

// K7: copy-branch scatter: probs[b, tok] += mix1*alpha
__global__ __launch_bounds__(256) void k7_scatter(const int* __restrict__ memids,
                                                  const float* __restrict__ ws,
                                                  float* __restrict__ probs)
{
    int idx = blockIdx.x*256 + threadIdx.x;   // NB*MZV = 65536
    int b = idx >> 11, mz = idx & 2047;
    float gm = ws[WS_GSTATW + b*2], gs = ws[WS_GSTATW + b*2 + 1];
    float mix1 = ws[WS_MIX + b*2 + 1];
    float alpha = __expf(ws[WS_W + b*MZV + mz] - gm) / gs;
    int tok = memids[b*MZV + mz];
    atomicAdd(&probs[(long)b*VOC + tok], mix1 * alpha);
}

extern "C" void kernel_launch(void* const* d_in, const int* in_sizes, int n_in,
                              void* d_out, int out_size, void* d_ws, size_t ws_size,
                              hipStream_t stream)
{
    const float* enc        = (const float*)d_in[0];
    const float* encsumm    = (const float*)d_in[1];
    const float* embsumm    = (const float*)d_in[2];
    const float* memencs    = (const float*)d_in[3];
    // d_in[4] = memencsumm: provably unused (zeros in both concat middles)
    const float* memembsumm = (const float*)d_in[5];
    const float* memmask    = (const float*)d_in[6];
    const int*   memids     = (const int*)d_in[7];
    const float* W_out      = (const float*)d_in[8];
    const float* b_out      = (const float*)d_in[9];
    const float* W_mix      = (const float*)d_in[10];
    const float* b_mix      = (const float*)d_in[11];
    const float* unk        = (const float*)d_in[12];
    float* out = (float*)d_out;
    float* ws  = (float*)d_ws;

    hipLaunchKernelGGL(k0_stageh, dim3(NB), dim3(256), 0, stream, encsumm, enc, ws);
    hipLaunchKernelGGL(k1_mem, dim3(NB*MM), dim3(256), 0, stream,
                       enc, embsumm, memencs, memembsumm, memmask, ws);
    hipLaunchKernelGGL(k2_comb, dim3(NB), dim3(256), 0, stream,
                       encsumm, enc, W_mix, b_mix, out, ws);
    hipLaunchKernelGGL(k4_gemm, dim3((VOC + 63)/64), dim3(256), 0, stream,
                       (const unsigned short*)(ws + WS_H), W_out, b_out, unk, out);
    hipLaunchKernelGGL(k5_gstat, dim3(32, NB), dim3(256), 0, stream, out, ws);
    hipLaunchKernelGGL(k6_final, dim3((VOC + 255)/256, NB), dim3(256), 0, stream, out, ws);
    hipLaunchKernelGGL(k7_scatter, dim3(NB*MZV/256), dim3(256), 0, stream, memids, ws, out);
}

// Round 9
// 140.567 us; speedup vs baseline: 1.0121x; 1.0121x over previous
//
#include <hip/hip_runtime.h>
#include <hip/hip_bf16.h>

#define NB   32
#define DIMK 512
#define MM   32
#define ZZ   64
#define MZV  2048
#define VOC  50257

typedef __attribute__((ext_vector_type(8))) short  short8;   // 8 bf16 = 4 VGPR
typedef __attribute__((ext_vector_type(4))) float  f32x4;
typedef __attribute__((ext_vector_type(8))) unsigned short ushort8;

// ws layout in floats
#define WS_W      0                       // [NB][MZV] raw scores (incl. log mask)
#define WS_PVEC   (WS_W + NB*MZV)         // [NB][MM][DIMK] partial weighted vecs
#define WS_LSTAT  (WS_PVEC + NB*MM*DIMK)  // [NB][MM][2] (max, sum)
#define WS_GSTATW (WS_LSTAT + NB*MM*2)    // [NB][2] global (max,sum) copy branch
#define WS_MIX    (WS_GSTATW + NB*2)      // [NB][2]
#define WS_GPART  (WS_MIX + NB*2)         // [NB][32][2] gen softmax partials
#define WS_H      (WS_GPART + NB*32*2)    // [NB][1024] bf16 h (as ushort)

// pack 8 f32 -> 8 bf16 (RNE) via v_cvt_pk_bf16_f32 (compiler-generated)
__device__ __forceinline__ ushort8 cvt8(float4 a, float4 b) {
    union { ushort8 u; __hip_bfloat162 h[4]; } r;
    r.h[0] = __float22bfloat162_rn(make_float2(a.x, a.y));
    r.h[1] = __float22bfloat162_rn(make_float2(a.z, a.w));
    r.h[2] = __float22bfloat162_rn(make_float2(b.x, b.y));
    r.h[3] = __float22bfloat162_rn(make_float2(b.z, b.w));
    return r.u;
}

// K0: h = concat(encsumm, enc) converted to bf16, contiguous per batch
__global__ void k0_stageh(const float* __restrict__ encsumm, const float* __restrict__ enc,
                          float* __restrict__ ws)
{
    int b = blockIdx.x;
    int c = threadIdx.x * 4;                       // 0..1020
    const float* src = (c < DIMK) ? (encsumm + b*DIMK + c) : (enc + b*DIMK + (c - DIMK));
    float4 v = *(const float4*)src;
    union { ushort4 u; __hip_bfloat162 h[2]; } o;
    o.h[0] = __float22bfloat162_rn(make_float2(v.x, v.y));
    o.h[1] = __float22bfloat162_rn(make_float2(v.z, v.w));
    *(ushort4*)((unsigned short*)(ws + WS_H) + b*1024 + c) = o.u;
}

// K1: per (b,m) block — scores + online-softmax weighted sum, memencs read ONCE
__global__ __launch_bounds__(256) void k1_mem(
    const float* __restrict__ enc, const float* __restrict__ embsumm,
    const float* __restrict__ memencs, const float* __restrict__ memembsumm,
    const float* __restrict__ memmask, float* __restrict__ ws)
{
    int blk = blockIdx.x;
    int b = blk >> 5, m = blk & 31;
    int tid = threadIdx.x, wid = tid >> 6, lane = tid & 63;
    int c0 = lane * 4, c1 = c0 + 256;
    const float* encb = enc + b * DIMK;
    const float* embb = embsumm + b * DIMK;
    float4 qe0 = *(const float4*)(encb + c0);
    float4 qe1 = *(const float4*)(encb + c1);
    float4 qm0 = *(const float4*)(embb + c0);
    float4 qm1 = *(const float4*)(embb + c1);
    const float* meb = memencs    + (long)(b*MM + m) * ZZ * DIMK;
    const float* mmb = memembsumm + (long)(b*MM + m) * ZZ * DIMK;
    const float* mkb = memmask    + (long)(b*MM + m) * ZZ;
    float* w_ws = ws + WS_W + b*MZV + m*ZZ;

    float lmax = -3.0e38f, lsum = 0.f;
    float4 a0 = make_float4(0.f,0.f,0.f,0.f), a1 = make_float4(0.f,0.f,0.f,0.f);

    for (int z = wid; z < ZZ; z += 4) {
        const float* mer = meb + z*DIMK;
        const float* mmr = mmb + z*DIMK;
        float4 e0 = *(const float4*)(mer + c0);
        float4 e1 = *(const float4*)(mer + c1);
        float4 s0 = *(const float4*)(mmr + c0);
        float4 s1 = *(const float4*)(mmr + c1);
        float d = e0.x*qe0.x + e0.y*qe0.y + e0.z*qe0.z + e0.w*qe0.w
                + e1.x*qe1.x + e1.y*qe1.y + e1.z*qe1.z + e1.w*qe1.w
                + s0.x*qm0.x + s0.y*qm0.y + s0.z*qm0.z + s0.w*qm0.w
                + s1.x*qm1.x + s1.y*qm1.y + s1.z*qm1.z + s1.w*qm1.w;
        #pragma unroll
        for (int off = 32; off; off >>= 1) d += __shfl_xor(d, off);
        d += logf(mkb[z]);                 // mask=1 -> +0; mask=0 -> -inf
        if (lane == 0) w_ws[z] = d;
        float nm = fmaxf(lmax, d);
        float sc = __expf(lmax - nm);
        float e  = __expf(d - nm);
        lsum = lsum * sc + e;
        a0.x = a0.x*sc + e*e0.x; a0.y = a0.y*sc + e*e0.y;
        a0.z = a0.z*sc + e*e0.z; a0.w = a0.w*sc + e*e0.w;
        a1.x = a1.x*sc + e*e1.x; a1.y = a1.y*sc + e*e1.y;
        a1.z = a1.z*sc + e*e1.z; a1.w = a1.w*sc + e*e1.w;
        lmax = nm;
    }

    __shared__ float sacc[4][DIMK];
    __shared__ float sst[4][2];
    *(float4*)&sacc[wid][c0] = a0;
    *(float4*)&sacc[wid][c1] = a1;
    if (lane == 0) { sst[wid][0] = lmax; sst[wid][1] = lsum; }
    __syncthreads();
    float bm = fmaxf(fmaxf(sst[0][0], sst[1][0]), fmaxf(sst[2][0], sst[3][0]));
    float sc0 = __expf(sst[0][0]-bm), sc1 = __expf(sst[1][0]-bm);
    float sc2 = __expf(sst[2][0]-bm), sc3 = __expf(sst[3][0]-bm);
    float bs = sst[0][1]*sc0 + sst[1][1]*sc1 + sst[2][1]*sc2 + sst[3][1]*sc3;
    int d0 = tid * 2;
    float2 v0 = *(float2*)&sacc[0][d0];
    float2 v1 = *(float2*)&sacc[1][d0];
    float2 v2 = *(float2*)&sacc[2][d0];
    float2 v3 = *(float2*)&sacc[3][d0];
    float p0 = v0.x*sc0 + v1.x*sc1 + v2.x*sc2 + v3.x*sc3;
    float p1 = v0.y*sc0 + v1.y*sc1 + v2.y*sc2 + v3.y*sc3;
    float* pv = ws + WS_PVEC + (long)(b*MM+m)*DIMK + d0;
    pv[0] = p0; pv[1] = p1;
    if (tid == 0) { float* ls = ws + WS_LSTAT + (b*MM+m)*2; ls[0] = bm; ls[1] = bs; }
}

// K2: combine the 32 m-partials per b -> mem_enc_summ (output 1) + global (max,sum)
// + (merged k3) mixer gates computed by wave 0
__global__ __launch_bounds__(256) void k2_comb(
    const float* __restrict__ encsumm, const float* __restrict__ enc,
    const float* __restrict__ W_mix, const float* __restrict__ b_mix,
    float* __restrict__ out, float* __restrict__ ws)
{
    int b = blockIdx.x, tid = threadIdx.x;
    const float* ls = ws + WS_LSTAT + b*MM*2;
    float gm = -3.0e38f;
    #pragma unroll
    for (int m = 0; m < MM; m++) gm = fmaxf(gm, ls[m*2]);
    float gs = 0.f;
    #pragma unroll
    for (int m = 0; m < MM; m++) gs += ls[m*2+1] * __expf(ls[m*2] - gm);
    if (tid == 0) { ws[WS_GSTATW + b*2] = gm; ws[WS_GSTATW + b*2 + 1] = gs; }
    float inv = 1.0f / gs;
    int d0 = tid * 2;
    float p0 = 0.f, p1 = 0.f;
    for (int m = 0; m < MM; m++) {
        float sc = __expf(ls[m*2] - gm);
        const float* pv = ws + WS_PVEC + (long)(b*MM+m)*DIMK + d0;
        p0 += pv[0]*sc; p1 += pv[1]*sc;
    }
    out[(long)NB*VOC + b*DIMK + d0]     = p0 * inv;
    out[(long)NB*VOC + b*DIMK + d0 + 1] = p1 * inv;

    // ---- merged mixer (wave 0 only) ----
    if (tid < 64) {
        int l = tid;
        float m0 = 0.f, m1 = 0.f;
        #pragma unroll
        for (int p = 0; p < 4; p++) {
            int cc = l*4 + p*256;
            float4 h4 = (cc < 512) ? *(const float4*)(encsumm + b*DIMK + cc)
                                   : *(const float4*)(enc + b*DIMK + cc - 512);
            float4 w0 = *(const float4*)(W_mix + cc);
            float4 w1 = *(const float4*)(W_mix + 1024 + cc);
            m0 += h4.x*w0.x + h4.y*w0.y + h4.z*w0.z + h4.w*w0.w;
            m1 += h4.x*w1.x + h4.y*w1.y + h4.z*w1.z + h4.w*w1.w;
        }
        #pragma unroll
        for (int off = 32; off; off >>= 1) { m0 += __shfl_xor(m0, off); m1 += __shfl_xor(m1, off); }
        if (l == 0) {
            m0 += b_mix[0]; m1 += b_mix[1];
            float mx = fmaxf(m0, m1);
            float e0 = __expf(m0-mx), e1 = __expf(m1-mx);
            float s = e0 + e1;
            ws[WS_MIX + b*2] = e0/s; ws[WS_MIX + b*2 + 1] = e1/s;
        }
    }
}

// K4 v9 (MFMA, small tiles, high stream count): block = 32 v x 32 b, 4 waves
// (wave = one 16x16 D tile; wv = v-half, wb = b-half). Grid 1571 -> 6 blocks/CU
// = 6 independent barrier groups per SIMD (vs 3 before). Chunk = 64 k,
// double-buffered LDS (2x4KB W-bf16 + 2x4KB A), one barrier per chunk.
// Per thread per chunk: 2 W float4 + 1 A ushort8 loads, 4 cvt_pk, 2 ds_writes.
__global__ __launch_bounds__(256, 6) void k4_gemm(
    const unsigned short* __restrict__ hbf,
    const float* __restrict__ W_out, const float* __restrict__ b_out,
    const float* __restrict__ unk, float* __restrict__ logits)
{
    __shared__ __align__(16) unsigned short b_lds[2][8*32*8];   // 2 x 4 KB
    __shared__ __align__(16) unsigned short a_lds[2][8*32*8];   // 2 x 4 KB
    int tid = threadIdx.x, wid = tid >> 6, lane = tid & 63;
    int wv = wid >> 1, wb = wid & 1;
    int vt = blockIdx.x * 32;

    // staging: thread owns row r (0..31), granule gq (0..7) = 8 elems at k=gq*8
    int r = tid >> 3, gq = tid & 7;
    long grow = min(vt + r, VOC - 1);
    const float* wbase = W_out + grow * 1024 + gq * 8;
    const unsigned short* abase = hbf + r * 1024 + gq * 8;

    int lg = lane >> 4, ln = lane & 15;

    f32x4 acc = {0.f,0.f,0.f,0.f};
    float4 f0, f1; ushort8 av;

    int bw = (gq*32 + (r ^ ((gq & 3) << 2))) * 8;
    int aw = (gq*32 + (r ^ gq)) * 8;

#define LOADC(c) do { const float* wp = wbase + (c)*64;            \
        f0 = *(const float4*)(wp); f1 = *(const float4*)(wp+4);    \
        av = *(const ushort8*)(abase + (c)*64); } while (0)
#define WRITEC(buf) do {                            \
        *(ushort8*)&b_lds[buf][bw] = cvt8(f0, f1);  \
        *(ushort8*)&a_lds[buf][aw] = av; } while (0)

    LOADC(0); WRITEC(0);
    LOADC(1);
    __syncthreads();

    for (int c = 0; c < 16; ++c) {
        int buf = c & 1;
        #pragma unroll
        for (int s = 0; s < 2; ++s) {
            int g = s*4 + lg;
            short8 bfrag = *(const short8*)&b_lds[buf][(g*32 + ((wv*16 + ln) ^ ((g & 3) << 2)))*8];
            short8 afrag = *(const short8*)&a_lds[buf][(g*32 + ((wb*16 + ln) ^ g))*8];
            acc = __builtin_amdgcn_mfma_f32_16x16x32_bf16(afrag, bfrag, acc, 0, 0, 0);
        }
        if (c < 15) {
            WRITEC(buf ^ 1);            // waits only on the loads for chunk c+1
            if (c < 14) LOADC(c + 2);   // next loads go in flight across barrier
        }
        __syncthreads();
    }
#undef LOADC
#undef WRITEC

    // epilogue: C/D layout col=lane&15, row=(lane>>4)*4+reg  (m89-verified)
    int v = vt + wv*16 + ln;
    if (v < VOC) {
        float bias = b_out[v] + logf(unk[v]);
        #pragma unroll
        for (int rr = 0; rr < 4; ++rr) {
            int m = wb*16 + lg*4 + rr;
            logits[(long)m*VOC + v] = acc[rr] + bias;
        }
    }
}

// K5: gen softmax stats, 32 chunks per b
__global__ __launch_bounds__(256) void k5_gstat(const float* __restrict__ logits, float* __restrict__ ws)
{
    int chunk = blockIdx.x, b = blockIdx.y, tid = threadIdx.x;
    const int CH = (VOC + 31) / 32;
    int v0 = chunk * CH;
    int v1 = min(VOC, v0 + CH);
    float m = -3.0e38f, s = 0.f;
    for (int v = v0 + tid; v < v1; v += 256) {
        float x = logits[(long)b*VOC + v];
        float nm = fmaxf(m, x);
        s = s*__expf(m - nm) + __expf(x - nm);
        m = nm;
    }
    #pragma unroll
    for (int off = 32; off; off >>= 1) {
        float om = __shfl_xor(m, off), os = __shfl_xor(s, off);
        float nm = fmaxf(m, om);
        s = s*__expf(m - nm) + os*__expf(om - nm);
        m = nm;
    }
    __shared__ float sm[4], ssum[4];
    int wid = tid >> 6, lane = tid & 63;
    if (lane == 0) { sm[wid] = m; ssum[wid] = s; }
    __syncthreads();
    if (tid == 0) {
        float gm = fmaxf(fmaxf(sm[0], sm[1]), fmaxf(sm[2], sm[3]));
        float gs = ssum[0]*__expf(sm[0]-gm) + ssum[1]*__expf(sm[1]-gm)
                 + ssum[2]*__expf(sm[2]-gm) + ssum[3]*__expf(sm[3]-gm);
        ws[WS_GPART + (b*32 + chunk)*2]     = gm;
        ws[WS_GPART + (b*32 + chunk)*2 + 1] = gs;
    }
}

// K6: probs = mix0 * softmax(logits), in place; merges the 32 chunk partials inline
__global__ __launch_bounds__(256) void k6_final(float* __restrict__ probs, const float* __restrict__ ws)
{
    int v = blockIdx.x*256 + threadIdx.x;
    int b = blockIdx.y;
    float gm = -3.0e38f;
    #pragma unroll
    for (int i = 0; i < 32; ++i) gm = fmaxf(gm, ws[WS_GPART + (b*32+i)*2]);
    float gs = 0.f;
    #pragma unroll
    for (int i = 0; i < 32; ++i)
        gs += ws[WS_GPART + (b*32+i)*2 + 1] * __expf(ws[WS_GPART + (b*32+i)*2] - gm);
    if (v >= VOC) return;
    float mix0 = ws[WS_MIX + b*2];
    long idx = (long)b*VOC + v;
    probs[idx] = mix0 * __expf(probs[idx] - gm) / gs;
}

// K7: copy-branch scatter: probs[b, tok] += mix1*alpha
__global__ __launch_bounds__(256) void k7_scatter(const int* __restrict__ memids,
                                                  const float* __restrict__ ws,
                                                  float* __restrict__ probs)
{
    int idx = blockIdx.x*256 + threadIdx.x;   // NB*MZV = 65536
    int b = idx >> 11, mz = idx & 2047;
    float gm = ws[WS_GSTATW + b*2], gs = ws[WS_GSTATW + b*2 + 1];
    float mix1 = ws[WS_MIX + b*2 + 1];
    float alpha = __expf(ws[WS_W + b*MZV + mz] - gm) / gs;
    int tok = memids[b*MZV + mz];
    atomicAdd(&probs[(long)b*VOC + tok], mix1 * alpha);
}

extern "C" void kernel_launch(void* const* d_in, const int* in_sizes, int n_in,
                              void* d_out, int out_size, void* d_ws, size_t ws_size,
                              hipStream_t stream)
{
    const float* enc        = (const float*)d_in[0];
    const float* encsumm    = (const float*)d_in[1];
    const float* embsumm    = (const float*)d_in[2];
    const float* memencs    = (const float*)d_in[3];
    // d_in[4] = memencsumm: provably unused (zeros in both concat middles)
    const float* memembsumm = (const float*)d_in[5];
    const float* memmask    = (const float*)d_in[6];
    const int*   memids     = (const int*)d_in[7];
    const float* W_out      = (const float*)d_in[8];
    const float* b_out      = (const float*)d_in[9];
    const float* W_mix      = (const float*)d_in[10];
    const float* b_mix      = (const float*)d_in[11];
    const float* unk        = (const float*)d_in[12];
    float* out = (float*)d_out;
    float* ws  = (float*)d_ws;

    hipLaunchKernelGGL(k0_stageh, dim3(NB), dim3(256), 0, stream, encsumm, enc, ws);
    hipLaunchKernelGGL(k1_mem, dim3(NB*MM), dim3(256), 0, stream,
                       enc, embsumm, memencs, memembsumm, memmask, ws);
    hipLaunchKernelGGL(k2_comb, dim3(NB), dim3(256), 0, stream,
                       encsumm, enc, W_mix, b_mix, out, ws);
    hipLaunchKernelGGL(k4_gemm, dim3((VOC + 31)/32), dim3(256), 0, stream,
                       (const unsigned short*)(ws + WS_H), W_out, b_out, unk, out);
    hipLaunchKernelGGL(k5_gstat, dim3(32, NB), dim3(256), 0, stream, out, ws);
    hipLaunchKernelGGL(k6_final, dim3((VOC + 255)/256, NB), dim3(256), 0, stream, out, ws);
    hipLaunchKernelGGL(k7_scatter, dim3(NB*MZV/256), dim3(256), 0, stream, memids, ws, out);
}